// Round 17
// baseline (420.343 us; speedup 1.0000x reference)
//
#include <hip/hip_runtime.h>
#include <hip/hip_bf16.h>
#include <cstddef>
#include <cstdint>

#define TPB 256
#define HID 128
#define GATD 512
#define HEADS 4

typedef __attribute__((ext_vector_type(8))) short bf16x8;
typedef __attribute__((ext_vector_type(4))) float f32x4;

__device__ __forceinline__ float lrelu02(float x) { return x > 0.0f ? x : 0.2f * x; }

__device__ __forceinline__ unsigned short f2bf_rn(float f) {
  uint32_t u = __float_as_uint(f);
  u += 0x7fff + ((u >> 16) & 1);
  return (unsigned short)(u >> 16);
}
__device__ __forceinline__ float bf2f(unsigned short h) {
  return __uint_as_float(((uint32_t)h) << 16);
}
__device__ __forceinline__ float bflo(uint32_t u) { return __uint_as_float(u << 16); }
__device__ __forceinline__ float bfhi(uint32_t u) { return __uint_as_float(u & 0xffff0000u); }

// ---------------- utility ----------------
__global__ void k_zero(int* __restrict__ p, int n) {
  int i = blockIdx.x * blockDim.x + threadIdx.x;
  if (i < n) p[i] = 0;
}

// ---------------- CSR build ----------------
__global__ void k_hist(const int* __restrict__ dst, int* __restrict__ cnt, int E) {
  int i = blockIdx.x * blockDim.x + threadIdx.x;
  if (i < E) atomicAdd(&cnt[dst[i]], 1);
}

__global__ __launch_bounds__(256) void k_scan_blk(const int* __restrict__ cnt,
                                                  int* __restrict__ rowp,
                                                  int* __restrict__ bsum,
                                                  float* __restrict__ dinv, int n) {
  __shared__ int wsum[4];
  const int tid = threadIdx.x, lane = tid & 63, wid = tid >> 6;
  const int base = blockIdx.x * 1024 + tid * 4;
  int v[4];
#pragma unroll
  for (int q = 0; q < 4; ++q) {
    int idx = base + q;
    v[q] = (idx < n) ? cnt[idx] : 0;
    if (idx < n) dinv[idx] = rsqrtf((float)(v[q] + 1));  // +1 self loop
  }
  int s = v[0] + v[1] + v[2] + v[3];
  int sc = s;
#pragma unroll
  for (int off = 1; off < 64; off <<= 1) {
    int t = __shfl_up(sc, off);
    if (lane >= off) sc += t;
  }
  if (lane == 63) wsum[wid] = sc;
  __syncthreads();
  int woff = 0;
#pragma unroll
  for (int w = 0; w < 4; ++w)
    if (w < wid) woff += wsum[w];
  int run = woff + sc - s;
#pragma unroll
  for (int q = 0; q < 4; ++q) {
    int idx = base + q;
    if (idx < n) rowp[idx] = run;
    run += v[q];
  }
  if (tid == 255) bsum[blockIdx.x] = woff + sc;
}

__global__ __launch_bounds__(256) void k_scan_top(int* __restrict__ bsum, int nb) {
  __shared__ int sm[256];
  const int tid = threadIdx.x;
  int v = (tid < nb) ? bsum[tid] : 0;
  sm[tid] = v;
  __syncthreads();
  for (int off = 1; off < 256; off <<= 1) {
    int t = (tid >= off) ? sm[tid - off] : 0;
    __syncthreads();
    sm[tid] += t;
    __syncthreads();
  }
  int incl = sm[tid];
  if (tid < nb) bsum[tid] = incl - v;
  if (tid == nb - 1) bsum[nb] = incl;
}

__global__ void k_scan_add(int* __restrict__ rowp, const int* __restrict__ bsum,
                           int n, int nb) {
  int i = blockIdx.x * blockDim.x + threadIdx.x;
  if (i < n) rowp[i] += bsum[i >> 10];
  if (i == 0) rowp[n] = bsum[nb];
}

__global__ void k_fill(const int* __restrict__ src, const int* __restrict__ dst,
                       const int* __restrict__ rowp, int* __restrict__ cur,
                       int* __restrict__ colsrc, int E) {
  int i = blockIdx.x * blockDim.x + threadIdx.x;
  if (i < E) {
    int d = dst[i];
    int pos = rowp[d] + atomicAdd(&cur[d], 1);
    colsrc[pos] = src[i];
  }
}

// ---------------- weight split (transposed hi/lo planes): Win, Wg1, Wg2, Wout ----------------
__global__ void k_splitw_all(const float* __restrict__ Win, const float* __restrict__ Wg1,
                             const float* __restrict__ Wg2, const float* __restrict__ Wout,
                             unsigned short* __restrict__ WinTh, unsigned short* __restrict__ WinTl,
                             unsigned short* __restrict__ Wg1Th, unsigned short* __restrict__ Wg1Tl,
                             unsigned short* __restrict__ Wg2Th, unsigned short* __restrict__ Wg2Tl,
                             unsigned short* __restrict__ WoutTh, unsigned short* __restrict__ WoutTl) {
  int t = blockIdx.x * blockDim.x + threadIdx.x;
  const float* W;
  unsigned short *H, *L;
  int K, NC, r;
  if (t < 32768)      { W = Win;  H = WinTh;  L = WinTl;  K = 256; NC = 128; r = t; }
  else if (t < 49152) { W = Wg1;  H = Wg1Th;  L = Wg1Tl;  K = 128; NC = 128; r = t - 32768; }
  else if (t < 65536) { W = Wg2;  H = Wg2Th;  L = Wg2Tl;  K = 128; NC = 128; r = t - 49152; }
  else if (t < 73728) { W = Wout; H = WoutTh; L = WoutTl; K = 128; NC = 64;  r = t - 65536; }
  else return;
  int k = r / NC, n2 = r % NC;
  float v = W[r];
  unsigned short h = f2bf_rn(v);
  H[(size_t)n2 * K + k] = h;
  L[(size_t)n2 * K + k] = f2bf_rn(v - bf2f(h));
}

// ---------------- merged prep: waT logits-fold, V2 planes (u-GEMM B), cbias ----------------
__global__ __launch_bounds__(256) void k_prep(const float* __restrict__ Wgat,
                                              const float* __restrict__ att_src,
                                              const float* __restrict__ att_dst,
                                              const float* __restrict__ Wao,
                                              const float* __restrict__ bgat,
                                              const float* __restrict__ bao,
                                              float* __restrict__ waT,
                                              unsigned short* __restrict__ V2Th,
                                              unsigned short* __restrict__ V2Tl,
                                              float* __restrict__ cb) {
  int t = blockIdx.x * blockDim.x + threadIdx.x;
  if (t < 1024) {
    int p = t >> 7, k = t & 127;
    int h = p & 3;
    const float* av = (p < 4 ? att_src : att_dst) + h * HID;
    const float* wrow = Wgat + (size_t)k * GATD + h * HID;
    float s = 0.f;
#pragma unroll 4
    for (int c = 0; c < HID; ++c) s = fmaf(wrow[c], av[c], s);
    waT[t] = s;
  } else if (t < 1024 + 65536) {
    int r = t - 1024;
    int j = r >> 7, k = r & 127;
    int c = j >> 2, h = j & 3;
    const float* wg = Wgat + (size_t)k * GATD + h * HID;
    const float* wa = Wao + (size_t)(h * HID) * HID + c;
    float s = 0.f;
#pragma unroll 4
    for (int d = 0; d < HID; ++d) s = fmaf(wg[d], wa[(size_t)d * HID], s);
    unsigned short hi = f2bf_rn(s);
    V2Th[(size_t)c * GATD + k * 4 + h] = hi;
    V2Tl[(size_t)c * GATD + k * 4 + h] = f2bf_rn(s - bf2f(hi));
  } else if (t < 1024 + 65536 + 128) {
    int c = t - 1024 - 65536;
    float s = bao[c];
    for (int d = 0; d < GATD; ++d) s = fmaf(bgat[d], Wao[(size_t)d * HID + c], s);
    cb[c] = s;
  }
}

// ---------------- weight-stationary MFMA GEMM, single-bf16 A, hi/lo B ----------------
// C = act(A @ W + bias)[*rowsc]; W as (BhT,BlT)[NC,KTOT] in LDS per chunk.
// AMODE 0: A = bf16.  AMODE 1: A = fp32, converted in regs.
// OUTM: 0=f32 out, 1=bf16 out.  SCALE: multiply row by rowsc[grow] before store.
template <int KTOT, int KC, int NCB, bool RELU, bool BIAS, int OUTM, int AMODE, bool SCALE>
__global__ __launch_bounds__(256) void k_gemm6(
    const void* __restrict__ Av,
    const unsigned short* __restrict__ BhT, const unsigned short* __restrict__ BlT,
    const float* __restrict__ bias, const float* __restrict__ rowsc,
    void* __restrict__ Cv, int M, int NC) {
  constexpr int NSUB = KC / 32;
  constexpr int NCHUNK = KTOT / KC;
  constexpr int NCF = NCB / 16;
  constexpr int UNITS = NSUB * 2 * 4 * NCB;
  __shared__ alignas(16) unsigned short Bs[NSUB][2][4][NCB][8];
  const int tid = threadIdx.x, lane = tid & 63, wid = tid >> 6;
  const int m0 = blockIdx.x * 64;
  const int n0 = blockIdx.y * NCB;
  const int fr = lane & 15, g = lane >> 4;
  const int arow = m0 + wid * 16 + fr;
  const bool aok = arow < M;
  const size_t abase = (size_t)arow * KTOT;

  f32x4 acc[NCF];
#pragma unroll
  for (int cf = 0; cf < NCF; ++cf) acc[cf] = (f32x4){0.f, 0.f, 0.f, 0.f};

  for (int c = 0; c < NCHUNK; ++c) {
    const int c0 = c * KC;
    if (c > 0) __syncthreads();
#pragma unroll
    for (int it = 0; it < UNITS / 256; ++it) {
      const int u = tid + it * 256;
      const int n = u % NCB;
      int rest = u / NCB;
      const int kg = rest & 3;
      rest >>= 2;
      const int p = rest & 1;
      const int sub = rest >> 1;
      const unsigned short* sp =
          (p ? BlT : BhT) + (size_t)(n0 + n) * KTOT + c0 + sub * 32 + kg * 8;
      *(uint4*)&Bs[sub][p][kg][n][0] = *(const uint4*)sp;
    }
    __syncthreads();
#pragma unroll
    for (int sub = 0; sub < NSUB; ++sub) {
      const int kb = c0 + sub * 32 + g * 8;
      bf16x8 a = {};
      if (aok) {
        if (AMODE == 0) {
          a = *(const bf16x8*)((const unsigned short*)Av + abase + kb);
        } else {
          const float* Af = (const float*)Av + abase + kb;
          float4 q0 = *(const float4*)Af;
          float4 q1 = *(const float4*)(Af + 4);
          float av[8] = {q0.x, q0.y, q0.z, q0.w, q1.x, q1.y, q1.z, q1.w};
          union { bf16x8 v; uint32_t u4[4]; } Hu;
#pragma unroll
          for (int q = 0; q < 4; ++q) {
            Hu.u4[q] = (uint32_t)f2bf_rn(av[2 * q]) | ((uint32_t)f2bf_rn(av[2 * q + 1]) << 16);
          }
          a = Hu.v;
        }
      }
#pragma unroll
      for (int cf = 0; cf < NCF; ++cf) {
        bf16x8 b_h = *(const bf16x8*)&Bs[sub][0][g][cf * 16 + fr][0];
        bf16x8 b_l = *(const bf16x8*)&Bs[sub][1][g][cf * 16 + fr][0];
        acc[cf] = __builtin_amdgcn_mfma_f32_16x16x32_bf16(a, b_h, acc[cf], 0, 0, 0);
        acc[cf] = __builtin_amdgcn_mfma_f32_16x16x32_bf16(a, b_l, acc[cf], 0, 0, 0);
      }
    }
  }
#pragma unroll
  for (int cf = 0; cf < NCF; ++cf) {
    const int col = n0 + cf * 16 + fr;
    const float bv = BIAS ? bias[col] : 0.f;
#pragma unroll
    for (int r = 0; r < 4; ++r) {
      const int grow = m0 + wid * 16 + g * 4 + r;
      if (grow < M) {
        float v = acc[cf][r] + bv;
        if (RELU) v = fmaxf(v, 0.f);
        if (SCALE) v *= rowsc[grow];
        const size_t idx = (size_t)grow * NC + col;
        if (OUTM == 0) ((float*)Cv)[idx] = v;
        else ((unsigned short*)Cv)[idx] = f2bf_rn(v);
      }
    }
  }
}

// ---------------- GCN aggregate (pre-scaled bf16 table: plain sum) + LN (+residual, +logits) ----------------
// xws rows are pre-scaled by dinv[src]; a = di * (xws[i] + sum_s xws[s]) + bias.
template <bool L2>
__global__ __launch_bounds__(256) void k_gcn_agg(
    const unsigned short* __restrict__ xws, const float* __restrict__ dinv,
    const int* __restrict__ rowp, const int* __restrict__ colsrc,
    const float* __restrict__ bias, const float* __restrict__ gamma,
    const float* __restrict__ beta,
    const unsigned short* __restrict__ resb,
    unsigned short* __restrict__ ob,
    const float* __restrict__ waT, float* __restrict__ a_s, float* __restrict__ a_d,
    int n) {
  __shared__ float w[8][HID];
  if (L2) {
    for (int t = threadIdx.x; t < 8 * HID; t += 256) ((float*)w)[t] = waT[t];
    __syncthreads();
  }
  const int lane = threadIdx.x & 63;
  const int i = blockIdx.x * 4 + (threadIdx.x >> 6);
  if (i >= n) return;
  const float di = dinv[i];
  const int c = lane * 2;
  uint32_t v0 = *(const uint32_t*)(xws + (size_t)i * HID + c);
  float a0 = bflo(v0), a1 = bfhi(v0);  // self loop (pre-scaled)
  float b0 = 0.f, b1 = 0.f;
  const int e0 = rowp[i], e1 = rowp[i + 1];
  int j = e0;
  for (; j + 7 < e1; j += 8) {
    int ss[8];
    uint32_t uu[8];
#pragma unroll
    for (int q = 0; q < 8; ++q) ss[q] = colsrc[j + q];
#pragma unroll
    for (int q = 0; q < 8; ++q) uu[q] = *(const uint32_t*)(xws + (size_t)ss[q] * HID + c);
#pragma unroll
    for (int q = 0; q < 8; ++q) {
      if (q & 1) {
        b0 += bflo(uu[q]);
        b1 += bfhi(uu[q]);
      } else {
        a0 += bflo(uu[q]);
        a1 += bfhi(uu[q]);
      }
    }
  }
  for (; j < e1; ++j) {
    int s0 = colsrc[j];
    uint32_t u0 = *(const uint32_t*)(xws + (size_t)s0 * HID + c);
    a0 += bflo(u0);
    a1 += bfhi(u0);
  }
  a0 = (a0 + b0) * di + bias[c];
  a1 = (a1 + b1) * di + bias[c + 1];
  float s1 = a0 + a1, s2 = a0 * a0 + a1 * a1;
#pragma unroll
  for (int m = 32; m >= 1; m >>= 1) {
    s1 += __shfl_xor(s1, m);
    s2 += __shfl_xor(s2, m);
  }
  float mu = s1 * (1.0f / HID);
  float var = s2 * (1.0f / HID) - mu * mu;
  float rstd = rsqrtf(var + 1e-5f);
  float y0 = fmaxf((a0 - mu) * rstd * gamma[c] + beta[c], 0.0f);
  float y1 = fmaxf((a1 - mu) * rstd * gamma[c + 1] + beta[c + 1], 0.0f);
  if (L2) {
    uint32_t rb = *(const uint32_t*)(resb + (size_t)i * HID + c);
    y0 += bflo(rb);
    y1 += bfhi(rb);
  }
  *(uint32_t*)(ob + (size_t)i * HID + c) =
      (uint32_t)f2bf_rn(y0) | ((uint32_t)f2bf_rn(y1) << 16);
  if (L2) {
    float p[8];
#pragma unroll
    for (int h = 0; h < 8; ++h) p[h] = y0 * w[h][c] + y1 * w[h][c + 1];
#pragma unroll
    for (int m = 32; m >= 1; m >>= 1) {
#pragma unroll
      for (int h = 0; h < 8; ++h) p[h] += __shfl_xor(p[h], m);
    }
    if (lane == 0) {
      a_s[i * 4 + 0] = p[0]; a_s[i * 4 + 1] = p[1];
      a_s[i * 4 + 2] = p[2]; a_s[i * 4 + 3] = p[3];
      a_d[i * 4 + 0] = p[4]; a_d[i * 4 + 1] = p[5];
      a_d[i * 4 + 2] = p[6]; a_d[i * 4 + 3] = p[7];
    }
  }
}

// ---------------- GAT 2-pass online-softmax aggregate on x2: u_h[i] = sum alpha_h x2[s] ----------------
// Pass 1: max. Pass 2 (chunked): unnormalized e-weighted accumulation + per-lane denom partials.
// Normalize at end. Output u[N][512] bf16, j = k*4+h head-interleaved.
__global__ __launch_bounds__(256) void k_gat_agg4(const unsigned short* __restrict__ x2b,
                                                  const float* __restrict__ a_s,
                                                  const float* __restrict__ a_d,
                                                  const int* __restrict__ rowp,
                                                  const int* __restrict__ colsrc,
                                                  unsigned short* __restrict__ ub,
                                                  int n) {
  __shared__ float4 albuf[4][64];
  __shared__ int sbuf[4][64];
  const int lane = threadIdx.x & 63;
  const int wid = threadIdx.x >> 6;
  const int i = blockIdx.x * 4 + wid;
  if (i >= n) return;
  const float4 adv = *(const float4*)(a_d + i * 4);
  const float4 asv = *(const float4*)(a_s + i * 4);
  float es0 = lrelu02(asv.x + adv.x);
  float es1 = lrelu02(asv.y + adv.y);
  float es2 = lrelu02(asv.z + adv.z);
  float es3 = lrelu02(asv.w + adv.w);
  const int e0 = rowp[i], e1 = rowp[i + 1];
  // pass 1: max
  float m0 = es0, m1 = es1, m2 = es2, m3 = es3;
  for (int j = e0 + lane; j < e1; j += 64) {
    int s = colsrc[j];
    const float4 av = *(const float4*)(a_s + s * 4);
    m0 = fmaxf(m0, lrelu02(av.x + adv.x));
    m1 = fmaxf(m1, lrelu02(av.y + adv.y));
    m2 = fmaxf(m2, lrelu02(av.z + adv.z));
    m3 = fmaxf(m3, lrelu02(av.w + adv.w));
  }
#pragma unroll
  for (int m = 32; m >= 1; m >>= 1) {
    m0 = fmaxf(m0, __shfl_xor(m0, m));
    m1 = fmaxf(m1, __shfl_xor(m1, m));
    m2 = fmaxf(m2, __shfl_xor(m2, m));
    m3 = fmaxf(m3, __shfl_xor(m3, m));
  }
  // self terms
  const float e_self0 = __expf(es0 - m0), e_self1 = __expf(es1 - m1);
  const float e_self2 = __expf(es2 - m2), e_self3 = __expf(es3 - m3);
  // unnormalized accumulators: col c0=lane*2 (heads 0-3), col c0+1 (heads 0-3)
  const int c0 = lane * 2;
  uint32_t sv = *(const uint32_t*)(x2b + (size_t)i * HID + c0);
  float x0 = bflo(sv), x1 = bfhi(sv);
  float4 A0 = make_float4(x0 * e_self0, x0 * e_self1, x0 * e_self2, x0 * e_self3);
  float4 A1 = make_float4(x1 * e_self0, x1 * e_self1, x1 * e_self2, x1 * e_self3);
  float dp0 = 0.f, dp1 = 0.f, dp2 = 0.f, dp3 = 0.f;  // per-lane denom partials
  // pass 2: chunked -- 64 lanes compute 64 edge e-values, then stream x2 rows
  for (int b = e0; b < e1; b += 64) {
    int j = b + lane;
    if (j < e1) {
      int s = colsrc[j];
      const float4 av = *(const float4*)(a_s + s * 4);
      float e0v = __expf(lrelu02(av.x + adv.x) - m0);
      float e1v = __expf(lrelu02(av.y + adv.y) - m1);
      float e2v = __expf(lrelu02(av.z + adv.z) - m2);
      float e3v = __expf(lrelu02(av.w + adv.w) - m3);
      dp0 += e0v; dp1 += e1v; dp2 += e2v; dp3 += e3v;
      albuf[wid][lane] = make_float4(e0v, e1v, e2v, e3v);
      sbuf[wid][lane] = s;
    }
    asm volatile("s_waitcnt lgkmcnt(0)" ::: "memory");
    const int cnt = min(64, e1 - b);
    for (int t = 0; t < cnt; ++t) {
      float4 a4 = albuf[wid][t];
      int s = sbuf[wid][t];
      uint32_t wv = *(const uint32_t*)(x2b + (size_t)s * HID + c0);
      float w0 = bflo(wv), w1 = bfhi(wv);
      A0.x = fmaf(w0, a4.x, A0.x); A0.y = fmaf(w0, a4.y, A0.y);
      A0.z = fmaf(w0, a4.z, A0.z); A0.w = fmaf(w0, a4.w, A0.w);
      A1.x = fmaf(w1, a4.x, A1.x); A1.y = fmaf(w1, a4.y, A1.y);
      A1.z = fmaf(w1, a4.z, A1.z); A1.w = fmaf(w1, a4.w, A1.w);
    }
  }
  // reduce denom partials across lanes, add self once (wave-uniform)
#pragma unroll
  for (int m = 32; m >= 1; m >>= 1) {
    dp0 += __shfl_xor(dp0, m);
    dp1 += __shfl_xor(dp1, m);
    dp2 += __shfl_xor(dp2, m);
    dp3 += __shfl_xor(dp3, m);
  }
  const float inv0 = 1.0f / (dp0 + e_self0), inv1 = 1.0f / (dp1 + e_self1);
  const float inv2 = 1.0f / (dp2 + e_self2), inv3 = 1.0f / (dp3 + e_self3);
  A0.x *= inv0; A0.y *= inv1; A0.z *= inv2; A0.w *= inv3;
  A1.x *= inv0; A1.y *= inv1; A1.z *= inv2; A1.w *= inv3;
  uint4 o;
  o.x = (uint32_t)f2bf_rn(A0.x) | ((uint32_t)f2bf_rn(A0.y) << 16);
  o.y = (uint32_t)f2bf_rn(A0.z) | ((uint32_t)f2bf_rn(A0.w) << 16);
  o.z = (uint32_t)f2bf_rn(A1.x) | ((uint32_t)f2bf_rn(A1.y) << 16);
  o.w = (uint32_t)f2bf_rn(A1.z) | ((uint32_t)f2bf_rn(A1.w) << 16);
  *(uint4*)(ub + (size_t)i * GATD + lane * 8) = o;
}

extern "C" void kernel_launch(void* const* d_in, const int* in_sizes, int n_in,
                              void* d_out, int out_size, void* d_ws, size_t ws_size,
                              hipStream_t stream) {
  const float* x = (const float*)d_in[0];
  const int* ei = (const int*)d_in[1];
  const float* Win = (const float*)d_in[2];
  const float* bin = (const float*)d_in[3];
  const float* Wg1 = (const float*)d_in[4];
  const float* bg1 = (const float*)d_in[5];
  const float* g1g = (const float*)d_in[6];
  const float* g1b = (const float*)d_in[7];
  const float* Wg2 = (const float*)d_in[8];
  const float* bg2 = (const float*)d_in[9];
  const float* g2g = (const float*)d_in[10];
  const float* g2b = (const float*)d_in[11];
  const float* Wgat = (const float*)d_in[12];
  const float* att_s = (const float*)d_in[13];
  const float* att_d = (const float*)d_in[14];
  const float* bgat = (const float*)d_in[15];
  const float* Wao = (const float*)d_in[16];
  const float* bao = (const float*)d_in[17];
  const float* Wout = (const float*)d_in[18];
  const float* bout = (const float*)d_in[19];

  const int N = in_sizes[0] / 256;
  const int E = in_sizes[1] / 2;
  const int* src = ei;
  const int* dst = ei + E;

  // ---- workspace layout (bytes), ~120 MB ----
  char* base = (char*)d_ws;
  size_t off = 0;
  unsigned short* h0b = (unsigned short*)(base + off); off += (size_t)N * HID * 2;
  unsigned short* x1b = (unsigned short*)(base + off); off += (size_t)N * HID * 2;
  unsigned short* xwb = (unsigned short*)(base + off); off += (size_t)N * HID * 2;
  unsigned short* x2b = (unsigned short*)(base + off); off += (size_t)N * HID * 2;
  unsigned short* ub = (unsigned short*)(base + off); off += (size_t)N * GATD * 2;
  unsigned short* attb = h0b;  // h0 dead after Wg1 GEMM; att written after
  float* dinv = (float*)(base + off);                 off += (size_t)N * 4;
  float* a_s = (float*)(base + off);                  off += (size_t)N * 16;
  float* a_d = (float*)(base + off);                  off += (size_t)N * 16;
  float* waT = (float*)(base + off);                  off += 4096;
  float* cb = (float*)(base + off);                   off += 512;
  unsigned short *WinTh, *WinTl, *Wg1Th, *Wg1Tl, *Wg2Th, *Wg2Tl, *V2Th, *V2Tl;
  unsigned short *WoutTh, *WoutTl;
  WinTh = (unsigned short*)(base + off); off += 256 * 128 * 2;
  WinTl = (unsigned short*)(base + off); off += 256 * 128 * 2;
  Wg1Th = (unsigned short*)(base + off); off += 128 * 128 * 2;
  Wg1Tl = (unsigned short*)(base + off); off += 128 * 128 * 2;
  Wg2Th = (unsigned short*)(base + off); off += 128 * 128 * 2;
  Wg2Tl = (unsigned short*)(base + off); off += 128 * 128 * 2;
  V2Th = (unsigned short*)(base + off);  off += 512 * 128 * 2;
  V2Tl = (unsigned short*)(base + off);  off += 512 * 128 * 2;
  WoutTh = (unsigned short*)(base + off); off += 128 * 64 * 2;
  WoutTl = (unsigned short*)(base + off); off += 128 * 64 * 2;
  int* rowp = (int*)(base + off);   off += (size_t)(N + 1) * 4;
  int* colsrc = (int*)(base + off); off += (size_t)E * 4;
  const int nb2 = (N + 1023) / 1024;
  int* bsum = (int*)(base + off);   off += (size_t)(nb2 + 2) * 4;
  int* cnt = (int*)ub;  // alias: dead before ub is written
  int* cur = cnt + N;

  const int eb = (E + TPB - 1) / TPB;
  const int zbk = (2 * N + TPB - 1) / TPB;
  const int ab = (N + 3) / 4;
  const int gm = (N + 63) / 64;

  // CSR + prep
  k_zero<<<zbk, TPB, 0, stream>>>(cnt, 2 * N);
  k_hist<<<eb, TPB, 0, stream>>>(dst, cnt, E);
  k_scan_blk<<<nb2, 256, 0, stream>>>(cnt, rowp, bsum, dinv, N);
  k_scan_top<<<1, 256, 0, stream>>>(bsum, nb2);
  k_scan_add<<<(N + 255) / 256, 256, 0, stream>>>(rowp, bsum, N, nb2);
  k_fill<<<eb, TPB, 0, stream>>>(src, dst, rowp, cur, colsrc, E);
  k_prep<<<(1024 + 65536 + 128 + 255) / 256, 256, 0, stream>>>(
      Wgat, att_s, att_d, Wao, bgat, bao, waT, V2Th, V2Tl, cb);
  k_splitw_all<<<(73728 + 255) / 256, 256, 0, stream>>>(
      Win, Wg1, Wg2, Wout, WinTh, WinTl, Wg1Th, Wg1Tl, Wg2Th, Wg2Tl, WoutTh, WoutTl);

  // h0 = relu(x @ Win + bin) -> bf16     [fp32 A converted in regs]
  k_gemm6<256, 64, 128, true, true, 1, 1, false><<<dim3(gm, 1), 256, 0, stream>>>(
      x, WinTh, WinTl, bin, nullptr, h0b, N, 128);
  // GCN layer 1: xws = bf16(dinv * (h0 @ Wg1))  [row pre-scaled]
  k_gemm6<128, 64, 128, false, false, 1, 0, true><<<dim3(gm, 1), 256, 0, stream>>>(
      h0b, Wg1Th, Wg1Tl, nullptr, dinv, xwb, N, 128);
  k_gcn_agg<false><<<ab, 256, 0, stream>>>(xwb, dinv, rowp, colsrc, bg1, g1g, g1b,
                                           nullptr, x1b, nullptr, nullptr, nullptr, N);
  // GCN layer 2 (+residual, +fused GAT logits)
  k_gemm6<128, 64, 128, false, false, 1, 0, true><<<dim3(gm, 1), 256, 0, stream>>>(
      x1b, Wg2Th, Wg2Tl, nullptr, dinv, xwb, N, 128);
  k_gcn_agg<true><<<ab, 256, 0, stream>>>(xwb, dinv, rowp, colsrc, bg2, g2g, g2b,
                                          x1b, x2b, waT, a_s, a_d, N);
  // GAT aggregate on x2 directly (V commuted out): u[N,512] bf16, 2-pass online softmax
  k_gat_agg4<<<ab, 256, 0, stream>>>(x2b, a_s, a_d, rowp, colsrc, ub, N);
  // att = relu(u @ V2 + cb) -> bf16 (attb aliases dead h0b)
  k_gemm6<512, 64, 128, true, true, 1, 0, false><<<dim3(gm, 1), 256, 0, stream>>>(
      ub, V2Th, V2Tl, cb, nullptr, attb, N, 128);
  // out = att @ Wout + bout -> fp32
  k_gemm6<128, 128, 64, false, true, 0, 0, false><<<dim3(gm, 1), 256, 0, stream>>>(
      attb, WoutTh, WoutTl, bout, nullptr, (float*)d_out, N, 64);
}

// Round 18
// 415.914 us; speedup vs baseline: 1.0106x; 1.0106x over previous
//
#include <hip/hip_runtime.h>
#include <hip/hip_bf16.h>
#include <cstddef>
#include <cstdint>

#define TPB 256
#define HID 128
#define GATD 512
#define HEADS 4

typedef __attribute__((ext_vector_type(8))) short bf16x8;
typedef __attribute__((ext_vector_type(4))) float f32x4;

__device__ __forceinline__ float lrelu02(float x) { return x > 0.0f ? x : 0.2f * x; }

__device__ __forceinline__ unsigned short f2bf_rn(float f) {
  uint32_t u = __float_as_uint(f);
  u += 0x7fff + ((u >> 16) & 1);
  return (unsigned short)(u >> 16);
}
__device__ __forceinline__ float bf2f(unsigned short h) {
  return __uint_as_float(((uint32_t)h) << 16);
}
__device__ __forceinline__ float bflo(uint32_t u) { return __uint_as_float(u << 16); }
__device__ __forceinline__ float bfhi(uint32_t u) { return __uint_as_float(u & 0xffff0000u); }

// ---------------- utility ----------------
__global__ void k_zero(int* __restrict__ p, int n) {
  int i = blockIdx.x * blockDim.x + threadIdx.x;
  if (i < n) p[i] = 0;
}

// ---------------- CSR build ----------------
__global__ void k_hist(const int* __restrict__ dst, int* __restrict__ cnt, int E) {
  int i = blockIdx.x * blockDim.x + threadIdx.x;
  if (i < E) atomicAdd(&cnt[dst[i]], 1);
}

__global__ __launch_bounds__(256) void k_scan_blk(const int* __restrict__ cnt,
                                                  int* __restrict__ rowp,
                                                  int* __restrict__ bsum,
                                                  float* __restrict__ dinv, int n) {
  __shared__ int wsum[4];
  const int tid = threadIdx.x, lane = tid & 63, wid = tid >> 6;
  const int base = blockIdx.x * 1024 + tid * 4;
  int v[4];
#pragma unroll
  for (int q = 0; q < 4; ++q) {
    int idx = base + q;
    v[q] = (idx < n) ? cnt[idx] : 0;
    if (idx < n) dinv[idx] = rsqrtf((float)(v[q] + 1));  // +1 self loop
  }
  int s = v[0] + v[1] + v[2] + v[3];
  int sc = s;
#pragma unroll
  for (int off = 1; off < 64; off <<= 1) {
    int t = __shfl_up(sc, off);
    if (lane >= off) sc += t;
  }
  if (lane == 63) wsum[wid] = sc;
  __syncthreads();
  int woff = 0;
#pragma unroll
  for (int w = 0; w < 4; ++w)
    if (w < wid) woff += wsum[w];
  int run = woff + sc - s;
#pragma unroll
  for (int q = 0; q < 4; ++q) {
    int idx = base + q;
    if (idx < n) rowp[idx] = run;
    run += v[q];
  }
  if (tid == 255) bsum[blockIdx.x] = woff + sc;
}

__global__ __launch_bounds__(256) void k_scan_top(int* __restrict__ bsum, int nb) {
  __shared__ int sm[256];
  const int tid = threadIdx.x;
  int v = (tid < nb) ? bsum[tid] : 0;
  sm[tid] = v;
  __syncthreads();
  for (int off = 1; off < 256; off <<= 1) {
    int t = (tid >= off) ? sm[tid - off] : 0;
    __syncthreads();
    sm[tid] += t;
    __syncthreads();
  }
  int incl = sm[tid];
  if (tid < nb) bsum[tid] = incl - v;
  if (tid == nb - 1) bsum[nb] = incl;
}

__global__ void k_scan_add(int* __restrict__ rowp, const int* __restrict__ bsum,
                           int n, int nb) {
  int i = blockIdx.x * blockDim.x + threadIdx.x;
  if (i < n) rowp[i] += bsum[i >> 10];
  if (i == 0) rowp[n] = bsum[nb];
}

__global__ void k_fill(const int* __restrict__ src, const int* __restrict__ dst,
                       const int* __restrict__ rowp, int* __restrict__ cur,
                       int* __restrict__ colsrc, int E) {
  int i = blockIdx.x * blockDim.x + threadIdx.x;
  if (i < E) {
    int d = dst[i];
    int pos = rowp[d] + atomicAdd(&cur[d], 1);
    colsrc[pos] = src[i];
  }
}

// ---------------- merged prep: weight splits + waT logits-fold + V2 planes + cbias ----------------
__global__ __launch_bounds__(256) void k_prep2(
    const float* __restrict__ Win, const float* __restrict__ Wg1,
    const float* __restrict__ Wg2, const float* __restrict__ Wout,
    const float* __restrict__ Wgat, const float* __restrict__ att_src,
    const float* __restrict__ att_dst, const float* __restrict__ Wao,
    const float* __restrict__ bgat, const float* __restrict__ bao,
    unsigned short* __restrict__ WinTh, unsigned short* __restrict__ WinTl,
    unsigned short* __restrict__ Wg1Th, unsigned short* __restrict__ Wg1Tl,
    unsigned short* __restrict__ Wg2Th, unsigned short* __restrict__ Wg2Tl,
    unsigned short* __restrict__ WoutTh, unsigned short* __restrict__ WoutTl,
    float* __restrict__ waT, unsigned short* __restrict__ V2Th,
    unsigned short* __restrict__ V2Tl, float* __restrict__ cb) {
  int t = blockIdx.x * blockDim.x + threadIdx.x;
  if (t < 73728) {
    // weight hi/lo transposed splits
    const float* W;
    unsigned short *H, *L;
    int K, NC, r;
    if (t < 32768)      { W = Win;  H = WinTh;  L = WinTl;  K = 256; NC = 128; r = t; }
    else if (t < 49152) { W = Wg1;  H = Wg1Th;  L = Wg1Tl;  K = 128; NC = 128; r = t - 32768; }
    else if (t < 65536) { W = Wg2;  H = Wg2Th;  L = Wg2Tl;  K = 128; NC = 128; r = t - 49152; }
    else                { W = Wout; H = WoutTh; L = WoutTl; K = 128; NC = 64;  r = t - 65536; }
    int k = r / NC, n2 = r % NC;
    float v = W[r];
    unsigned short h = f2bf_rn(v);
    H[(size_t)n2 * K + k] = h;
    L[(size_t)n2 * K + k] = f2bf_rn(v - bf2f(h));
  } else if (t < 73728 + 1024) {
    int r = t - 73728;
    int p = r >> 7, k = r & 127;
    int h = p & 3;
    const float* av = (p < 4 ? att_src : att_dst) + h * HID;
    const float* wrow = Wgat + (size_t)k * GATD + h * HID;
    float s = 0.f;
#pragma unroll 4
    for (int c = 0; c < HID; ++c) s = fmaf(wrow[c], av[c], s);
    waT[r] = s;
  } else if (t < 73728 + 1024 + 65536) {
    int r = t - 73728 - 1024;
    int j = r >> 7, k = r & 127;
    int c = j >> 2, h = j & 3;
    const float* wg = Wgat + (size_t)k * GATD + h * HID;
    const float* wa = Wao + (size_t)(h * HID) * HID + c;
    float s = 0.f;
#pragma unroll 4
    for (int d = 0; d < HID; ++d) s = fmaf(wg[d], wa[(size_t)d * HID], s);
    unsigned short hi = f2bf_rn(s);
    V2Th[(size_t)c * GATD + k * 4 + h] = hi;
    V2Tl[(size_t)c * GATD + k * 4 + h] = f2bf_rn(s - bf2f(hi));
  } else if (t < 73728 + 1024 + 65536 + 128) {
    int c = t - 73728 - 1024 - 65536;
    float s = bao[c];
    for (int d = 0; d < GATD; ++d) s = fmaf(bgat[d], Wao[(size_t)d * HID + c], s);
    cb[c] = s;
  }
}

// ---------------- weight-stationary MFMA GEMM, single-bf16 A, hi/lo B ----------------
template <int KTOT, int KC, int NCB, bool RELU, bool BIAS, int OUTM, int AMODE, bool SCALE>
__global__ __launch_bounds__(256) void k_gemm6(
    const void* __restrict__ Av,
    const unsigned short* __restrict__ BhT, const unsigned short* __restrict__ BlT,
    const float* __restrict__ bias, const float* __restrict__ rowsc,
    void* __restrict__ Cv, int M, int NC) {
  constexpr int NSUB = KC / 32;
  constexpr int NCHUNK = KTOT / KC;
  constexpr int NCF = NCB / 16;
  constexpr int UNITS = NSUB * 2 * 4 * NCB;
  __shared__ alignas(16) unsigned short Bs[NSUB][2][4][NCB][8];
  const int tid = threadIdx.x, lane = tid & 63, wid = tid >> 6;
  const int m0 = blockIdx.x * 64;
  const int n0 = blockIdx.y * NCB;
  const int fr = lane & 15, g = lane >> 4;
  const int arow = m0 + wid * 16 + fr;
  const bool aok = arow < M;
  const size_t abase = (size_t)arow * KTOT;

  f32x4 acc[NCF];
#pragma unroll
  for (int cf = 0; cf < NCF; ++cf) acc[cf] = (f32x4){0.f, 0.f, 0.f, 0.f};

  for (int c = 0; c < NCHUNK; ++c) {
    const int c0 = c * KC;
    if (c > 0) __syncthreads();
#pragma unroll
    for (int it = 0; it < UNITS / 256; ++it) {
      const int u = tid + it * 256;
      const int n = u % NCB;
      int rest = u / NCB;
      const int kg = rest & 3;
      rest >>= 2;
      const int p = rest & 1;
      const int sub = rest >> 1;
      const unsigned short* sp =
          (p ? BlT : BhT) + (size_t)(n0 + n) * KTOT + c0 + sub * 32 + kg * 8;
      *(uint4*)&Bs[sub][p][kg][n][0] = *(const uint4*)sp;
    }
    __syncthreads();
#pragma unroll
    for (int sub = 0; sub < NSUB; ++sub) {
      const int kb = c0 + sub * 32 + g * 8;
      bf16x8 a = {};
      if (aok) {
        if (AMODE == 0) {
          a = *(const bf16x8*)((const unsigned short*)Av + abase + kb);
        } else {
          const float* Af = (const float*)Av + abase + kb;
          float4 q0 = *(const float4*)Af;
          float4 q1 = *(const float4*)(Af + 4);
          float av[8] = {q0.x, q0.y, q0.z, q0.w, q1.x, q1.y, q1.z, q1.w};
          union { bf16x8 v; uint32_t u4[4]; } Hu;
#pragma unroll
          for (int q = 0; q < 4; ++q) {
            Hu.u4[q] = (uint32_t)f2bf_rn(av[2 * q]) | ((uint32_t)f2bf_rn(av[2 * q + 1]) << 16);
          }
          a = Hu.v;
        }
      }
#pragma unroll
      for (int cf = 0; cf < NCF; ++cf) {
        bf16x8 b_h = *(const bf16x8*)&Bs[sub][0][g][cf * 16 + fr][0];
        bf16x8 b_l = *(const bf16x8*)&Bs[sub][1][g][cf * 16 + fr][0];
        acc[cf] = __builtin_amdgcn_mfma_f32_16x16x32_bf16(a, b_h, acc[cf], 0, 0, 0);
        acc[cf] = __builtin_amdgcn_mfma_f32_16x16x32_bf16(a, b_l, acc[cf], 0, 0, 0);
      }
    }
  }
#pragma unroll
  for (int cf = 0; cf < NCF; ++cf) {
    const int col = n0 + cf * 16 + fr;
    const float bv = BIAS ? bias[col] : 0.f;
#pragma unroll
    for (int r = 0; r < 4; ++r) {
      const int grow = m0 + wid * 16 + g * 4 + r;
      if (grow < M) {
        float v = acc[cf][r] + bv;
        if (RELU) v = fmaxf(v, 0.f);
        if (SCALE) v *= rowsc[grow];
        const size_t idx = (size_t)grow * NC + col;
        if (OUTM == 0) ((float*)Cv)[idx] = v;
        else ((unsigned short*)Cv)[idx] = f2bf_rn(v);
      }
    }
  }
}

// ---------------- GCN aggregate (pre-scaled bf16 table: plain sum) + LN (+residual, +logits) ----------------
template <bool L2>
__global__ __launch_bounds__(256) void k_gcn_agg(
    const unsigned short* __restrict__ xws, const float* __restrict__ dinv,
    const int* __restrict__ rowp, const int* __restrict__ colsrc,
    const float* __restrict__ bias, const float* __restrict__ gamma,
    const float* __restrict__ beta,
    const unsigned short* __restrict__ resb,
    unsigned short* __restrict__ ob,
    const float* __restrict__ waT, float* __restrict__ a_s, float* __restrict__ a_d,
    int n) {
  __shared__ float w[8][HID];
  if (L2) {
    for (int t = threadIdx.x; t < 8 * HID; t += 256) ((float*)w)[t] = waT[t];
    __syncthreads();
  }
  const int lane = threadIdx.x & 63;
  const int i = blockIdx.x * 4 + (threadIdx.x >> 6);
  if (i >= n) return;
  const float di = dinv[i];
  const int c = lane * 2;
  uint32_t v0 = *(const uint32_t*)(xws + (size_t)i * HID + c);
  float a0 = bflo(v0), a1 = bfhi(v0);  // self loop (pre-scaled)
  float b0 = 0.f, b1 = 0.f;
  const int e0 = rowp[i], e1 = rowp[i + 1];
  int j = e0;
  for (; j + 7 < e1; j += 8) {
    int ss[8];
    uint32_t uu[8];
#pragma unroll
    for (int q = 0; q < 8; ++q) ss[q] = colsrc[j + q];
#pragma unroll
    for (int q = 0; q < 8; ++q) uu[q] = *(const uint32_t*)(xws + (size_t)ss[q] * HID + c);
#pragma unroll
    for (int q = 0; q < 8; ++q) {
      if (q & 1) {
        b0 += bflo(uu[q]);
        b1 += bfhi(uu[q]);
      } else {
        a0 += bflo(uu[q]);
        a1 += bfhi(uu[q]);
      }
    }
  }
  for (; j < e1; ++j) {
    int s0 = colsrc[j];
    uint32_t u0 = *(const uint32_t*)(xws + (size_t)s0 * HID + c);
    a0 += bflo(u0);
    a1 += bfhi(u0);
  }
  a0 = (a0 + b0) * di + bias[c];
  a1 = (a1 + b1) * di + bias[c + 1];
  float s1 = a0 + a1, s2 = a0 * a0 + a1 * a1;
#pragma unroll
  for (int m = 32; m >= 1; m >>= 1) {
    s1 += __shfl_xor(s1, m);
    s2 += __shfl_xor(s2, m);
  }
  float mu = s1 * (1.0f / HID);
  float var = s2 * (1.0f / HID) - mu * mu;
  float rstd = rsqrtf(var + 1e-5f);
  float y0 = fmaxf((a0 - mu) * rstd * gamma[c] + beta[c], 0.0f);
  float y1 = fmaxf((a1 - mu) * rstd * gamma[c + 1] + beta[c + 1], 0.0f);
  if (L2) {
    uint32_t rb = *(const uint32_t*)(resb + (size_t)i * HID + c);
    y0 += bflo(rb);
    y1 += bfhi(rb);
  }
  *(uint32_t*)(ob + (size_t)i * HID + c) =
      (uint32_t)f2bf_rn(y0) | ((uint32_t)f2bf_rn(y1) << 16);
  if (L2) {
    float p[8];
#pragma unroll
    for (int h = 0; h < 8; ++h) p[h] = y0 * w[h][c] + y1 * w[h][c + 1];
#pragma unroll
    for (int m = 32; m >= 1; m >>= 1) {
#pragma unroll
      for (int h = 0; h < 8; ++h) p[h] += __shfl_xor(p[h], m);
    }
    if (lane == 0) {
      a_s[i * 4 + 0] = p[0]; a_s[i * 4 + 1] = p[1];
      a_s[i * 4 + 2] = p[2]; a_s[i * 4 + 3] = p[3];
      a_d[i * 4 + 0] = p[4]; a_d[i * 4 + 1] = p[5];
      a_d[i * 4 + 2] = p[6]; a_d[i * 4 + 3] = p[7];
    }
  }
}

// ---------------- GAT 3-pass softmax-aggregate on x2 (R16 form): u_h[i] = sum alpha_h x2[s] ----------------
__global__ __launch_bounds__(256) void k_gat_agg4(const unsigned short* __restrict__ x2b,
                                                  const float* __restrict__ a_s,
                                                  const float* __restrict__ a_d,
                                                  const int* __restrict__ rowp,
                                                  const int* __restrict__ colsrc,
                                                  unsigned short* __restrict__ ub,
                                                  int n) {
  __shared__ float4 albuf[4][64];
  __shared__ int sbuf[4][64];
  const int lane = threadIdx.x & 63;
  const int wid = threadIdx.x >> 6;
  const int i = blockIdx.x * 4 + wid;
  if (i >= n) return;
  const float4 adv = *(const float4*)(a_d + i * 4);
  const float4 asv = *(const float4*)(a_s + i * 4);
  float es0 = lrelu02(asv.x + adv.x);
  float es1 = lrelu02(asv.y + adv.y);
  float es2 = lrelu02(asv.z + adv.z);
  float es3 = lrelu02(asv.w + adv.w);
  const int e0 = rowp[i], e1 = rowp[i + 1];
  // pass 1: max
  float m0 = es0, m1 = es1, m2 = es2, m3 = es3;
  for (int j = e0 + lane; j < e1; j += 64) {
    int s = colsrc[j];
    const float4 av = *(const float4*)(a_s + s * 4);
    m0 = fmaxf(m0, lrelu02(av.x + adv.x));
    m1 = fmaxf(m1, lrelu02(av.y + adv.y));
    m2 = fmaxf(m2, lrelu02(av.z + adv.z));
    m3 = fmaxf(m3, lrelu02(av.w + adv.w));
  }
#pragma unroll
  for (int m = 32; m >= 1; m >>= 1) {
    m0 = fmaxf(m0, __shfl_xor(m0, m));
    m1 = fmaxf(m1, __shfl_xor(m1, m));
    m2 = fmaxf(m2, __shfl_xor(m2, m));
    m3 = fmaxf(m3, __shfl_xor(m3, m));
  }
  // pass 2: denom
  float d0 = 0.f, d1 = 0.f, d2 = 0.f, d3 = 0.f;
  for (int j = e0 + lane; j < e1; j += 64) {
    int s = colsrc[j];
    const float4 av = *(const float4*)(a_s + s * 4);
    d0 += __expf(lrelu02(av.x + adv.x) - m0);
    d1 += __expf(lrelu02(av.y + adv.y) - m1);
    d2 += __expf(lrelu02(av.z + adv.z) - m2);
    d3 += __expf(lrelu02(av.w + adv.w) - m3);
  }
#pragma unroll
  for (int m = 32; m >= 1; m >>= 1) {
    d0 += __shfl_xor(d0, m);
    d1 += __shfl_xor(d1, m);
    d2 += __shfl_xor(d2, m);
    d3 += __shfl_xor(d3, m);
  }
  d0 += __expf(es0 - m0);
  d1 += __expf(es1 - m1);
  d2 += __expf(es2 - m2);
  d3 += __expf(es3 - m3);
  const float inv0 = 1.0f / d0, inv1 = 1.0f / d1, inv2 = 1.0f / d2, inv3 = 1.0f / d3;
  const float4 asf = make_float4(__expf(es0 - m0) * inv0, __expf(es1 - m1) * inv1,
                                 __expf(es2 - m2) * inv2, __expf(es3 - m3) * inv3);
  const int c0 = lane * 2;
  uint32_t sv = *(const uint32_t*)(x2b + (size_t)i * HID + c0);
  float x0 = bflo(sv), x1 = bfhi(sv);
  float4 A0 = make_float4(x0 * asf.x, x0 * asf.y, x0 * asf.z, x0 * asf.w);
  float4 A1 = make_float4(x1 * asf.x, x1 * asf.y, x1 * asf.z, x1 * asf.w);
  // pass 3: chunked -- 64 lanes compute 64 edge-alphas, then stream x2 rows (4B/lane/edge)
  for (int b = e0; b < e1; b += 64) {
    int j = b + lane;
    if (j < e1) {
      int s = colsrc[j];
      const float4 av = *(const float4*)(a_s + s * 4);
      albuf[wid][lane] = make_float4(__expf(lrelu02(av.x + adv.x) - m0) * inv0,
                                     __expf(lrelu02(av.y + adv.y) - m1) * inv1,
                                     __expf(lrelu02(av.z + adv.z) - m2) * inv2,
                                     __expf(lrelu02(av.w + adv.w) - m3) * inv3);
      sbuf[wid][lane] = s;
    }
    asm volatile("s_waitcnt lgkmcnt(0)" ::: "memory");
    const int cnt = min(64, e1 - b);
    for (int t = 0; t < cnt; ++t) {
      float4 a4 = albuf[wid][t];
      int s = sbuf[wid][t];
      uint32_t wv = *(const uint32_t*)(x2b + (size_t)s * HID + c0);
      float w0 = bflo(wv), w1 = bfhi(wv);
      A0.x = fmaf(w0, a4.x, A0.x); A0.y = fmaf(w0, a4.y, A0.y);
      A0.z = fmaf(w0, a4.z, A0.z); A0.w = fmaf(w0, a4.w, A0.w);
      A1.x = fmaf(w1, a4.x, A1.x); A1.y = fmaf(w1, a4.y, A1.y);
      A1.z = fmaf(w1, a4.z, A1.z); A1.w = fmaf(w1, a4.w, A1.w);
    }
  }
  uint4 o;
  o.x = (uint32_t)f2bf_rn(A0.x) | ((uint32_t)f2bf_rn(A0.y) << 16);
  o.y = (uint32_t)f2bf_rn(A0.z) | ((uint32_t)f2bf_rn(A0.w) << 16);
  o.z = (uint32_t)f2bf_rn(A1.x) | ((uint32_t)f2bf_rn(A1.y) << 16);
  o.w = (uint32_t)f2bf_rn(A1.z) | ((uint32_t)f2bf_rn(A1.w) << 16);
  *(uint4*)(ub + (size_t)i * GATD + lane * 8) = o;
}

extern "C" void kernel_launch(void* const* d_in, const int* in_sizes, int n_in,
                              void* d_out, int out_size, void* d_ws, size_t ws_size,
                              hipStream_t stream) {
  const float* x = (const float*)d_in[0];
  const int* ei = (const int*)d_in[1];
  const float* Win = (const float*)d_in[2];
  const float* bin = (const float*)d_in[3];
  const float* Wg1 = (const float*)d_in[4];
  const float* bg1 = (const float*)d_in[5];
  const float* g1g = (const float*)d_in[6];
  const float* g1b = (const float*)d_in[7];
  const float* Wg2 = (const float*)d_in[8];
  const float* bg2 = (const float*)d_in[9];
  const float* g2g = (const float*)d_in[10];
  const float* g2b = (const float*)d_in[11];
  const float* Wgat = (const float*)d_in[12];
  const float* att_s = (const float*)d_in[13];
  const float* att_d = (const float*)d_in[14];
  const float* bgat = (const float*)d_in[15];
  const float* Wao = (const float*)d_in[16];
  const float* bao = (const float*)d_in[17];
  const float* Wout = (const float*)d_in[18];
  const float* bout = (const float*)d_in[19];

  const int N = in_sizes[0] / 256;
  const int E = in_sizes[1] / 2;
  const int* src = ei;
  const int* dst = ei + E;

  // ---- workspace layout (bytes), ~120 MB ----
  char* base = (char*)d_ws;
  size_t off = 0;
  unsigned short* h0b = (unsigned short*)(base + off); off += (size_t)N * HID * 2;
  unsigned short* x1b = (unsigned short*)(base + off); off += (size_t)N * HID * 2;
  unsigned short* xwb = (unsigned short*)(base + off); off += (size_t)N * HID * 2;
  unsigned short* x2b = (unsigned short*)(base + off); off += (size_t)N * HID * 2;
  unsigned short* ub = (unsigned short*)(base + off); off += (size_t)N * GATD * 2;
  unsigned short* attb = h0b;  // h0 dead after Wg1 GEMM; att written after
  float* dinv = (float*)(base + off);                 off += (size_t)N * 4;
  float* a_s = (float*)(base + off);                  off += (size_t)N * 16;
  float* a_d = (float*)(base + off);                  off += (size_t)N * 16;
  float* waT = (float*)(base + off);                  off += 4096;
  float* cb = (float*)(base + off);                   off += 512;
  unsigned short *WinTh, *WinTl, *Wg1Th, *Wg1Tl, *Wg2Th, *Wg2Tl, *V2Th, *V2Tl;
  unsigned short *WoutTh, *WoutTl;
  WinTh = (unsigned short*)(base + off); off += 256 * 128 * 2;
  WinTl = (unsigned short*)(base + off); off += 256 * 128 * 2;
  Wg1Th = (unsigned short*)(base + off); off += 128 * 128 * 2;
  Wg1Tl = (unsigned short*)(base + off); off += 128 * 128 * 2;
  Wg2Th = (unsigned short*)(base + off); off += 128 * 128 * 2;
  Wg2Tl = (unsigned short*)(base + off); off += 128 * 128 * 2;
  V2Th = (unsigned short*)(base + off);  off += 512 * 128 * 2;
  V2Tl = (unsigned short*)(base + off);  off += 512 * 128 * 2;
  WoutTh = (unsigned short*)(base + off); off += 128 * 64 * 2;
  WoutTl = (unsigned short*)(base + off); off += 128 * 64 * 2;
  int* rowp = (int*)(base + off);   off += (size_t)(N + 1) * 4;
  int* colsrc = (int*)(base + off); off += (size_t)E * 4;
  const int nb2 = (N + 1023) / 1024;
  int* bsum = (int*)(base + off);   off += (size_t)(nb2 + 2) * 4;
  int* cnt = (int*)ub;  // alias: dead before ub is written
  int* cur = cnt + N;

  const int eb = (E + TPB - 1) / TPB;
  const int zbk = (2 * N + TPB - 1) / TPB;
  const int ab = (N + 3) / 4;
  const int gm = (N + 63) / 64;

  // CSR + prep
  k_zero<<<zbk, TPB, 0, stream>>>(cnt, 2 * N);
  k_hist<<<eb, TPB, 0, stream>>>(dst, cnt, E);
  k_scan_blk<<<nb2, 256, 0, stream>>>(cnt, rowp, bsum, dinv, N);
  k_scan_top<<<1, 256, 0, stream>>>(bsum, nb2);
  k_scan_add<<<(N + 255) / 256, 256, 0, stream>>>(rowp, bsum, N, nb2);
  k_fill<<<eb, TPB, 0, stream>>>(src, dst, rowp, cur, colsrc, E);
  k_prep2<<<(73728 + 1024 + 65536 + 128 + 255) / 256, 256, 0, stream>>>(
      Win, Wg1, Wg2, Wout, Wgat, att_s, att_d, Wao, bgat, bao,
      WinTh, WinTl, Wg1Th, Wg1Tl, Wg2Th, Wg2Tl, WoutTh, WoutTl,
      waT, V2Th, V2Tl, cb);

  // h0 = relu(x @ Win + bin) -> bf16     [fp32 A converted in regs]
  k_gemm6<256, 64, 128, true, true, 1, 1, false><<<dim3(gm, 1), 256, 0, stream>>>(
      x, WinTh, WinTl, bin, nullptr, h0b, N, 128);
  // GCN layer 1: xws = bf16(dinv * (h0 @ Wg1))  [row pre-scaled]
  k_gemm6<128, 64, 128, false, false, 1, 0, true><<<dim3(gm, 1), 256, 0, stream>>>(
      h0b, Wg1Th, Wg1Tl, nullptr, dinv, xwb, N, 128);
  k_gcn_agg<false><<<ab, 256, 0, stream>>>(xwb, dinv, rowp, colsrc, bg1, g1g, g1b,
                                           nullptr, x1b, nullptr, nullptr, nullptr, N);
  // GCN layer 2 (+residual, +fused GAT logits)
  k_gemm6<128, 64, 128, false, false, 1, 0, true><<<dim3(gm, 1), 256, 0, stream>>>(
      x1b, Wg2Th, Wg2Tl, nullptr, dinv, xwb, N, 128);
  k_gcn_agg<true><<<ab, 256, 0, stream>>>(xwb, dinv, rowp, colsrc, bg2, g2g, g2b,
                                          x1b, x2b, waT, a_s, a_d, N);
  // GAT aggregate on x2 directly (V commuted out): u[N,512] bf16
  k_gat_agg4<<<ab, 256, 0, stream>>>(x2b, a_s, a_d, rowp, colsrc, ub, N);
  // att = relu(u @ V2 + cb) -> bf16 (attb aliases dead h0b)
  k_gemm6<512, 64, 128, true, true, 1, 0, false><<<dim3(gm, 1), 256, 0, stream>>>(
      ub, V2Th, V2Tl, cb, nullptr, attb, N, 128);
  // out = att @ Wout + bout -> fp32
  k_gemm6<128, 128, 64, false, true, 0, 0, false><<<dim3(gm, 1), 256, 0, stream>>>(
      attb, WoutTh, WoutTl, bout, nullptr, (float*)d_out, N, 64);
}